// Round 4
// baseline (894.369 us; speedup 1.0000x reference)
//
#include <hip/hip_runtime.h>
#include <cstdint>
#include <cstddef>

#define CH 128
#define BM 64          // edges per k2 tile (256 threads, 4 waves)

typedef __attribute__((ext_vector_type(8))) short bf16x8;
typedef __attribute__((ext_vector_type(4))) float f32x4;

__device__ __forceinline__ unsigned short f2bf(float x){
    unsigned int u = __float_as_uint(x);
    u = (u + 0x7FFFu + ((u >> 16) & 1u)) >> 16;   // RNE
    return (unsigned short)u;
}
__device__ __forceinline__ float bf2f(unsigned short b){
    return __uint_as_float(((unsigned int)b) << 16);
}
__device__ __forceinline__ unsigned int pairadd_bf(unsigned int a, unsigned int b){
    float lo = bf2f((unsigned short)(a & 0xffff)) + bf2f((unsigned short)(b & 0xffff));
    float hi = bf2f((unsigned short)(a >> 16))    + bf2f((unsigned short)(b >> 16));
    return (unsigned int)f2bf(lo) | ((unsigned int)f2bf(hi) << 16);
}
__device__ __forceinline__ bf16x8 cvt8(float4 a, float4 b){
    union { uint4 u; bf16x8 v; } r;
    r.u.x = (unsigned int)f2bf(a.x) | ((unsigned int)f2bf(a.y) << 16);
    r.u.y = (unsigned int)f2bf(a.z) | ((unsigned int)f2bf(a.w) << 16);
    r.u.z = (unsigned int)f2bf(b.x) | ((unsigned int)f2bf(b.y) << 16);
    r.u.w = (unsigned int)f2bf(b.z) | ((unsigned int)f2bf(b.w) << 16);
    return r.v;
}

// ---------------------------------------------------------------------------
// k0: transpose+convert weights to bf16 wT[mat][n][k] (k contiguous); zero sums.
// ---------------------------------------------------------------------------
__global__ __launch_bounds__(256) void k0_prep(
        const float* __restrict__ w_self, const float* __restrict__ w_h,
        const float* __restrict__ w_t, unsigned short* __restrict__ wT,
        float* __restrict__ sums){
    int t = blockIdx.x * 256 + threadIdx.x;
    if (t < 256*256) sums[t] = 0.f;
    if (t < 3*CH*CH){
        int mat = t / (CH*CH);
        int r = t - mat*(CH*CH);
        int k = r >> 7, n = r & 127;
        const float* w = (mat == 0) ? w_self : ((mat == 1) ? w_h : w_t);
        wT[mat*CH*CH + n*CH + k] = f2bf(w[k*CH + n]);
    }
}

// ---------------------------------------------------------------------------
// k1: H = x @ w_h, T = x @ w_t  (bf16 out, f32 MFMA accumulate). Proven R0-R2.
// ---------------------------------------------------------------------------
__global__ __launch_bounds__(512) void k1_ht(
        const float* __restrict__ x, const unsigned short* __restrict__ wT,
        unsigned short* __restrict__ H, unsigned short* __restrict__ T, int N){
    __shared__ __align__(16) unsigned char smem[98304];
    const int tid = threadIdx.x;
    const int m0 = blockIdx.x * 128;
    #pragma unroll
    for (int i = 0; i < 8; ++i){
        int g = tid + i*512;
        int row = g >> 5, col4 = (g & 31) * 4;
        int rg = m0 + row; rg = rg < N ? rg : N-1;
        float4 v = *(const float4*)(x + (size_t)rg*CH + col4);
        unsigned int lo = (unsigned int)f2bf(v.x) | ((unsigned int)f2bf(v.y) << 16);
        unsigned int hi = (unsigned int)f2bf(v.z) | ((unsigned int)f2bf(v.w) << 16);
        unsigned int b = ((unsigned int)(row*256 + col4*2)) ^ ((unsigned int)(row & 7) << 4);
        *(uint2*)(smem + b) = make_uint2(lo, hi);
    }
    #pragma unroll
    for (int m = 0; m < 2; ++m){
        const unsigned short* src = wT + (m+1)*CH*CH;
        unsigned char* dst = smem + 32768 + m*32768;
        #pragma unroll
        for (int i = 0; i < 4; ++i){
            int g = tid + i*512;
            int n = g >> 4, k8 = (g & 15) * 8;
            uint4 v = *(const uint4*)(src + n*CH + k8);
            unsigned int b = ((unsigned int)(n*256 + k8*2)) ^ ((unsigned int)(n & 7) << 4);
            *(uint4*)(dst + b) = v;
        }
    }
    __syncthreads();
    const int lane = tid & 63, wv = tid >> 6;
    const int lr = lane & 15, lg = lane >> 4;
    f32x4 accH[8], accT[8];
    #pragma unroll
    for (int n = 0; n < 8; ++n){ accH[n] = (f32x4){0.f,0.f,0.f,0.f}; accT[n] = (f32x4){0.f,0.f,0.f,0.f}; }
    #pragma unroll
    for (int kk = 0; kk < 4; ++kk){
        int arow = wv*16 + lr;
        unsigned int ab = ((unsigned int)(arow*256 + kk*64 + lg*16)) ^ ((unsigned int)(arow & 7) << 4);
        bf16x8 a = *(const bf16x8*)(smem + ab);
        #pragma unroll
        for (int n = 0; n < 8; ++n){
            int cc = n*16 + lr;
            unsigned int bb = ((unsigned int)(cc*256 + kk*64 + lg*16)) ^ ((unsigned int)(cc & 7) << 4);
            bf16x8 bh = *(const bf16x8*)(smem + 32768 + bb);
            bf16x8 bt = *(const bf16x8*)(smem + 65536 + bb);
            accH[n] = __builtin_amdgcn_mfma_f32_16x16x32_bf16(a, bh, accH[n], 0, 0, 0);
            accT[n] = __builtin_amdgcn_mfma_f32_16x16x32_bf16(a, bt, accT[n], 0, 0, 0);
        }
    }
    #pragma unroll
    for (int n = 0; n < 8; ++n){
        int cc = n*16 + lr;
        #pragma unroll
        for (int j = 0; j < 4; ++j){
            int mr = m0 + wv*16 + lg*4 + j;
            if (mr < N){
                H[(size_t)mr*CH + cc] = f2bf(accH[n][j]);
                T[(size_t)mr*CH + cc] = f2bf(accT[n][j]);
            }
        }
    }
}

// ---------------------------------------------------------------------------
// k2 v4: software-pipelined multi-tile loop. Per tile:
//   cvt av->af + write R(LDS) | issue av(next) | u=h+t + write U(LDS) |
//   issue gathers(next) | raw lgkm-barrier (vmcnt NOT drained!) | MFMA |
//   epilogue from LDS | raw barrier.  eidx prefetched 2 tiles ahead.
// LDS: R 16K | U 16K | red 1K = 33.8KB.  3 blocks/CU.
// ---------------------------------------------------------------------------
template<int WRITE>
__global__ __launch_bounds__(256, 3) void k2_pass(
        const float* __restrict__ ea, const int* __restrict__ eidx,
        const unsigned short* __restrict__ wT,
        const unsigned short* __restrict__ Hm, const unsigned short* __restrict__ Tm,
        float* __restrict__ out, const float* __restrict__ sb,
        float* __restrict__ sums, int E, int nt){
    __shared__ __align__(16) unsigned char smem[33792];
    float* red = (float*)(smem + 32768);
    const int tid = threadIdx.x;
    const int lane = tid & 63, wv = tid >> 6;
    const int lr = lane & 15, lg = lane >> 4;
    const int bid = blockIdx.x;
    const int G = gridDim.x;
    const int arow = wv*16 + lr;                  // this thread's A row in tile

    if (tid < 256) red[tid] = WRITE ? sb[tid] : 0.f;

    int grow[4], gcol[4];
    #pragma unroll
    for (int i = 0; i < 4; ++i){ int g = tid + i*256; grow[i] = g >> 4; gcol[i] = g & 15; }

    // ---- prologue: tile t0 ----
    const int t0 = bid;
    int tmpr[4], tmpc[4];
    #pragma unroll
    for (int i = 0; i < 4; ++i){
        tmpr[i] = eidx[t0*BM + grow[i]];
        tmpc[i] = eidx[E + t0*BM + grow[i]];
    }
    int n1p = t0 + G; if (n1p >= nt) n1p = t0;
    int ri_c[4], ci_c[4];                          // eidx for tile t+G
    #pragma unroll
    for (int i = 0; i < 4; ++i){
        ri_c[i] = eidx[n1p*BM + grow[i]];
        ci_c[i] = eidx[E + n1p*BM + grow[i]];
    }
    uint4 hv[4], tv[4];
    #pragma unroll
    for (int i = 0; i < 4; ++i){
        hv[i] = *(const uint4*)(Hm + (size_t)tmpr[i]*CH + gcol[i]*8);
        tv[i] = *(const uint4*)(Tm + (size_t)tmpc[i]*CH + gcol[i]*8);
    }
    float4 av[8];
    {
        const float* ap = ea + ((size_t)t0*BM + arow)*CH;
        #pragma unroll
        for (int kk = 0; kk < 4; ++kk){
            av[kk*2]   = *(const float4*)(ap + kk*32 + lg*8);
            av[kk*2+1] = *(const float4*)(ap + kk*32 + lg*8 + 4);
        }
    }

    float sreg[8], ssreg[8];
    #pragma unroll
    for (int n = 0; n < 8; ++n){ sreg[n] = 0.f; ssreg[n] = 0.f; }

    for (int t = t0; t < nt; t += G){
        int n1 = t + G;  if (n1 >= nt) n1 = t;
        int n2 = n1 + G; if (n2 >= nt) n2 = n1;
        const size_t e0 = (size_t)t*BM;

        // step0: prefetch eidx two tiles ahead
        int ri_n[4], ci_n[4];
        #pragma unroll
        for (int i = 0; i < 4; ++i){
            ri_n[i] = eidx[n2*BM + grow[i]];
            ci_n[i] = eidx[E + n2*BM + grow[i]];
        }
        // step1: convert current A-tile, write residual R to LDS
        bf16x8 af[4];
        #pragma unroll
        for (int kk = 0; kk < 4; ++kk){
            af[kk] = cvt8(av[kk*2], av[kk*2+1]);
            unsigned int b = ((unsigned int)(arow*256 + kk*64 + lg*16))
                           ^ ((((unsigned int)arow >> 2) & 3u) << 5);
            *(bf16x8*)(smem + b) = af[kk];
        }
        // step2: issue next tile's A loads (overlap rest of this tile)
        {
            const float* ap = ea + ((size_t)n1*BM + arow)*CH;
            #pragma unroll
            for (int kk = 0; kk < 4; ++kk){
                av[kk*2]   = *(const float4*)(ap + kk*32 + lg*8);
                av[kk*2+1] = *(const float4*)(ap + kk*32 + lg*8 + 4);
            }
        }
        // step3: u = h + t -> U LDS
        #pragma unroll
        for (int i = 0; i < 4; ++i){
            uint4 u4;
            u4.x = pairadd_bf(hv[i].x, tv[i].x);
            u4.y = pairadd_bf(hv[i].y, tv[i].y);
            u4.z = pairadd_bf(hv[i].z, tv[i].z);
            u4.w = pairadd_bf(hv[i].w, tv[i].w);
            unsigned int b = ((unsigned int)(grow[i]*256 + gcol[i]*16))
                           ^ ((((unsigned int)grow[i] >> 2) & 3u) << 5);
            *(uint4*)(smem + 16384 + b) = u4;
        }
        // step4: issue next tile's gathers
        #pragma unroll
        for (int i = 0; i < 4; ++i){
            hv[i] = *(const uint4*)(Hm + (size_t)ri_c[i]*CH + gcol[i]*8);
            tv[i] = *(const uint4*)(Tm + (size_t)ci_c[i]*CH + gcol[i]*8);
        }
        #pragma unroll
        for (int i = 0; i < 4; ++i){ ri_c[i] = ri_n[i]; ci_c[i] = ci_n[i]; }

        // LDS-visible barrier WITHOUT vmcnt drain (prefetches stay in flight)
        asm volatile("s_waitcnt lgkmcnt(0)\n\ts_barrier" ::: "memory");

        // MFMA: out0 = A @ w_self, B-frags from global wT (L1-hot)
        f32x4 acc[8];
        #pragma unroll
        for (int n = 0; n < 8; ++n) acc[n] = (f32x4){0.f,0.f,0.f,0.f};
        #pragma unroll
        for (int kk = 0; kk < 4; ++kk){
            #pragma unroll
            for (int n = 0; n < 8; ++n){
                bf16x8 bw = *(const bf16x8*)(wT + (size_t)(n*16 + lr)*CH + kk*32 + lg*8);
                acc[n] = __builtin_amdgcn_mfma_f32_16x16x32_bf16(af[kk], bw, acc[n], 0, 0, 0);
            }
        }
        // epilogue (C/D: col=lane&15, row=(lane>>4)*4+reg)
        #pragma unroll
        for (int n = 0; n < 8; ++n){
            int cc = n*16 + lr;
            #pragma unroll
            for (int j = 0; j < 4; ++j){
                int ml = wv*16 + lg*4 + j;
                unsigned int b = ((unsigned int)(ml*256 + cc*2))
                               ^ ((((unsigned int)ml >> 2) & 3u) << 5);
                float u = bf2f(*(const unsigned short*)(smem + 16384 + b));
                float r = bf2f(*(const unsigned short*)(smem + b));
                float o0 = acc[n][j];
                float v = fmaf(o0, 0.5f*u, o0) + r;     // o0*(1+0.5(h+t)) + ea
                if (WRITE){
                    out[(e0 + ml)*CH + cc] = fmaxf(fmaf(v, red[cc], red[CH + cc]), 0.f);
                } else {
                    sreg[n] += v; ssreg[n] += v*v;
                }
            }
        }
        // protect LDS for next iteration's writes (reads all consumed above)
        asm volatile("s_barrier" ::: "memory");
    }

    if (!WRITE){
        #pragma unroll
        for (int n = 0; n < 8; ++n){
            float s = sreg[n], ss = ssreg[n];
            s  += __shfl_xor(s, 16);  s  += __shfl_xor(s, 32);
            ss += __shfl_xor(ss, 16); ss += __shfl_xor(ss, 32);
            if (lane < 16){
                atomicAdd(&red[n*16 + lr], s);
                atomicAdd(&red[CH + n*16 + lr], ss);
            }
        }
        __syncthreads();
        if (tid < 256) atomicAdd(&sums[(bid & 255)*256 + tid], red[tid]);
    }
}

// ---------------------------------------------------------------------------
// k3: reduce 256 slots -> per-channel scale/shift (sb)
// ---------------------------------------------------------------------------
__global__ __launch_bounds__(128) void k3_stats(
        const float* __restrict__ sums, const float* __restrict__ gamma,
        const float* __restrict__ beta, float* __restrict__ sb, float invE){
    int c = threadIdx.x;
    float s = 0.f, ss = 0.f;
    for (int i = 0; i < 256; ++i){ s += sums[i*256 + c]; ss += sums[i*256 + CH + c]; }
    float mean = s * invE;
    float var = ss * invE - mean*mean;     // biased variance (matches reference)
    float inv = rsqrtf(var + 1e-5f);
    float sc = gamma[c] * inv;
    sb[c] = sc;
    sb[CH + c] = beta[c] - mean * sc;
}

extern "C" void kernel_launch(void* const* d_in, const int* in_sizes, int n_in,
                              void* d_out, int out_size, void* d_ws, size_t ws_size,
                              hipStream_t stream) {
    const float* x      = (const float*)d_in[0];
    const int*   eidx   = (const int*)d_in[1];
    const float* ea     = (const float*)d_in[2];
    const float* w_self = (const float*)d_in[4];
    const float* w_h    = (const float*)d_in[5];
    const float* w_t    = (const float*)d_in[6];
    const float* gamma  = (const float*)d_in[7];
    const float* beta   = (const float*)d_in[8];
    float* out = (float*)d_out;

    const int N = in_sizes[0] / CH;     // 40000
    const int E = in_sizes[3];          // 640000
    const int nt = E / BM;              // 10000 tiles
    int G = 2000; if (G > nt) G = nt;   // uniform 5 tiles/block at E=640000

    float* sums = (float*)d_ws;                          // 256*256 f32
    float* sb   = sums + 256*256;                        // 256 f32
    unsigned short* wT = (unsigned short*)(sb + 256);    // 3*128*128 bf16
    unsigned short* H  = wT + 3*CH*CH;                   // N*128 bf16
    unsigned short* T  = H + (size_t)N*CH;               // N*128 bf16

    k0_prep<<<256, 256, 0, stream>>>(w_self, w_h, w_t, wT, sums);
    k1_ht  <<<(N + 127)/128, 512, 0, stream>>>(x, wT, H, T, N);
    k2_pass<0><<<G, 256, 0, stream>>>(ea, eidx, wT, H, T, nullptr, nullptr, sums, E, nt);
    k3_stats<<<1, 128, 0, stream>>>(sums, gamma, beta, sb, 1.0f/(float)E);
    k2_pass<1><<<G, 256, 0, stream>>>(ea, eidx, wT, H, T, out, sb, nullptr, E, nt);
}

// Round 5
// 535.852 us; speedup vs baseline: 1.6691x; 1.6691x over previous
//
#include <hip/hip_runtime.h>
#include <cstdint>
#include <cstddef>

#define CH 128

typedef __attribute__((ext_vector_type(8))) short bf16x8;
typedef __attribute__((ext_vector_type(4))) float f32x4;

__device__ __forceinline__ unsigned short f2bf(float x){
    unsigned int u = __float_as_uint(x);
    u = (u + 0x7FFFu + ((u >> 16) & 1u)) >> 16;   // RNE
    return (unsigned short)u;
}
__device__ __forceinline__ float bf2f(unsigned short b){
    return __uint_as_float(((unsigned int)b) << 16);
}
__device__ __forceinline__ unsigned int pairadd_bf(unsigned int a, unsigned int b){
    float lo = bf2f((unsigned short)(a & 0xffff)) + bf2f((unsigned short)(b & 0xffff));
    float hi = bf2f((unsigned short)(a >> 16))    + bf2f((unsigned short)(b >> 16));
    return (unsigned int)f2bf(lo) | ((unsigned int)f2bf(hi) << 16);
}

// ---------------------------------------------------------------------------
// k0: transpose+convert weights to bf16 wT[mat][n][k]; zero sums[256*256].
// ---------------------------------------------------------------------------
__global__ __launch_bounds__(256) void k0_prep(
        const float* __restrict__ w_self, const float* __restrict__ w_h,
        const float* __restrict__ w_t, unsigned short* __restrict__ wT,
        float* __restrict__ sums){
    int t = blockIdx.x * 256 + threadIdx.x;
    if (t < 256*256) sums[t] = 0.f;
    if (t < 3*CH*CH){
        int mat = t / (CH*CH);
        int r = t - mat*(CH*CH);
        int k = r >> 7, n = r & 127;
        const float* w = (mat == 0) ? w_self : ((mat == 1) ? w_h : w_t);
        wT[mat*CH*CH + n*CH + k] = f2bf(w[k*CH + n]);
    }
}

// ---------------------------------------------------------------------------
// k1: H = x @ w_h, T = x @ w_t  (bf16 out, f32 MFMA accumulate). Proven R0-R4.
// ---------------------------------------------------------------------------
__global__ __launch_bounds__(512) void k1_ht(
        const float* __restrict__ x, const unsigned short* __restrict__ wT,
        unsigned short* __restrict__ H, unsigned short* __restrict__ T, int N){
    __shared__ __align__(16) unsigned char smem[98304];
    const int tid = threadIdx.x;
    const int m0 = blockIdx.x * 128;
    #pragma unroll
    for (int i = 0; i < 8; ++i){
        int g = tid + i*512;
        int row = g >> 5, col4 = (g & 31) * 4;
        int rg = m0 + row; rg = rg < N ? rg : N-1;
        float4 v = *(const float4*)(x + (size_t)rg*CH + col4);
        unsigned int lo = (unsigned int)f2bf(v.x) | ((unsigned int)f2bf(v.y) << 16);
        unsigned int hi = (unsigned int)f2bf(v.z) | ((unsigned int)f2bf(v.w) << 16);
        unsigned int b = ((unsigned int)(row*256 + col4*2)) ^ ((unsigned int)(row & 7) << 4);
        *(uint2*)(smem + b) = make_uint2(lo, hi);
    }
    #pragma unroll
    for (int m = 0; m < 2; ++m){
        const unsigned short* src = wT + (m+1)*CH*CH;
        unsigned char* dst = smem + 32768 + m*32768;
        #pragma unroll
        for (int i = 0; i < 4; ++i){
            int g = tid + i*512;
            int n = g >> 4, k8 = (g & 15) * 8;
            uint4 v = *(const uint4*)(src + n*CH + k8);
            unsigned int b = ((unsigned int)(n*256 + k8*2)) ^ ((unsigned int)(n & 7) << 4);
            *(uint4*)(dst + b) = v;
        }
    }
    __syncthreads();
    const int lane = tid & 63, wv = tid >> 6;
    const int lr = lane & 15, lg = lane >> 4;
    f32x4 accH[8], accT[8];
    #pragma unroll
    for (int n = 0; n < 8; ++n){ accH[n] = (f32x4){0.f,0.f,0.f,0.f}; accT[n] = (f32x4){0.f,0.f,0.f,0.f}; }
    #pragma unroll
    for (int kk = 0; kk < 4; ++kk){
        int arow = wv*16 + lr;
        unsigned int ab = ((unsigned int)(arow*256 + kk*64 + lg*16)) ^ ((unsigned int)(arow & 7) << 4);
        bf16x8 a = *(const bf16x8*)(smem + ab);
        #pragma unroll
        for (int n = 0; n < 8; ++n){
            int cc = n*16 + lr;
            unsigned int bb = ((unsigned int)(cc*256 + kk*64 + lg*16)) ^ ((unsigned int)(cc & 7) << 4);
            bf16x8 bh = *(const bf16x8*)(smem + 32768 + bb);
            bf16x8 bt = *(const bf16x8*)(smem + 65536 + bb);
            accH[n] = __builtin_amdgcn_mfma_f32_16x16x32_bf16(a, bh, accH[n], 0, 0, 0);
            accT[n] = __builtin_amdgcn_mfma_f32_16x16x32_bf16(a, bt, accT[n], 0, 0, 0);
        }
    }
    #pragma unroll
    for (int n = 0; n < 8; ++n){
        int cc = n*16 + lr;
        #pragma unroll
        for (int j = 0; j < 4; ++j){
            int mr = m0 + wv*16 + lg*4 + j;
            if (mr < N){
                H[(size_t)mr*CH + cc] = f2bf(accH[n][j]);
                T[(size_t)mr*CH + cc] = f2bf(accT[n][j]);
            }
        }
    }
}

// ---------------------------------------------------------------------------
// k2g: pure gather kernel. U[e][:] = H[row[e]][:] + T[col[e]][:]  (bf16).
//   chunk = 16B of a row; 16 lanes cover one edge row (256B coalesced).
//   4-deep unroll -> 8 gathers in flight; no LDS, no barriers.
// ---------------------------------------------------------------------------
__global__ __launch_bounds__(256, 6) void k2g(
        const int* __restrict__ eidx,
        const unsigned short* __restrict__ Hm, const unsigned short* __restrict__ Tm,
        unsigned short* __restrict__ U, int E){
    const int nth = gridDim.x * 256;
    const int nchunk = E * 16;
    int base = blockIdx.x * 256 + threadIdx.x;
    for (; base < nchunk; base += nth*4){
        int idx[4]; bool ok[4]; int r[4], c[4];
        #pragma unroll
        for (int u = 0; u < 4; ++u){
            idx[u] = base + u*nth;
            ok[u] = idx[u] < nchunk;
            int e = ok[u] ? (idx[u] >> 4) : 0;
            r[u] = eidx[e];
            c[u] = eidx[E + e];
        }
        uint4 hv[4], tv[4];
        #pragma unroll
        for (int u = 0; u < 4; ++u){
            int ch = idx[u] & 15;
            if (ok[u]){
                hv[u] = *(const uint4*)(Hm + (size_t)r[u]*CH + ch*8);
                tv[u] = *(const uint4*)(Tm + (size_t)c[u]*CH + ch*8);
            }
        }
        #pragma unroll
        for (int u = 0; u < 4; ++u){
            if (ok[u]){
                uint4 o;
                o.x = pairadd_bf(hv[u].x, tv[u].x);
                o.y = pairadd_bf(hv[u].y, tv[u].y);
                o.z = pairadd_bf(hv[u].z, tv[u].z);
                o.w = pairadd_bf(hv[u].w, tv[u].w);
                *(uint4*)(U + (size_t)idx[u]*8) = o;
            }
        }
    }
}

// ---------------------------------------------------------------------------
// k2ab: pure streaming pass, one-shot 64-edge tile, 256 thr, LDS 33.8KB.
//   Stage ea contiguously -> A/R LDS tile (bf16, serves MFMA A AND residual).
//   Stage U tile -> LDS. MFMA B-frags from global wT (L1-hot, one-shot).
//   WRITE=0: per-channel sum/sumsq partials.  WRITE=1: fused BN+ReLU -> out.
// ---------------------------------------------------------------------------
template<int WRITE>
__global__ __launch_bounds__(256, 4) void k2ab(
        const float* __restrict__ ea, const unsigned short* __restrict__ U,
        const unsigned short* __restrict__ wT,
        float* __restrict__ out, const float* __restrict__ sb,
        float* __restrict__ sums, int E){
    __shared__ __align__(16) unsigned char smem[33792];  // A/R 16K | U 16K | red 1K
    float* red = (float*)(smem + 32768);
    const int tid = threadIdx.x;
    const size_t e0 = (size_t)blockIdx.x * 64;
    if (tid < 256) red[tid] = WRITE ? sb[tid] : 0.f;

    // issue ea loads (contiguous g-pattern: 1KB/wave-instr)
    float4 av[8];
    #pragma unroll
    for (int i = 0; i < 8; ++i){
        int g = tid + i*256;
        int row = g >> 5, col4 = (g & 31) * 4;
        av[i] = *(const float4*)(ea + (e0 + row)*CH + col4);
    }
    // issue U loads (contiguous)
    uint4 uv[4];
    #pragma unroll
    for (int i = 0; i < 4; ++i){
        int g = tid + i*256;
        int urow = g >> 4, uc = g & 15;
        uv[i] = *(const uint4*)(U + (e0 + urow)*CH + uc*8);
    }
    // stage ea -> bf16 A/R tile (swizzle (row&7)<<4, proven)
    #pragma unroll
    for (int i = 0; i < 8; ++i){
        int g = tid + i*256;
        int row = g >> 5, col4 = (g & 31) * 4;
        unsigned int lo = (unsigned int)f2bf(av[i].x) | ((unsigned int)f2bf(av[i].y) << 16);
        unsigned int hi = (unsigned int)f2bf(av[i].z) | ((unsigned int)f2bf(av[i].w) << 16);
        unsigned int b = ((unsigned int)(row*256 + col4*2)) ^ ((unsigned int)(row & 7) << 4);
        *(uint2*)(smem + b) = make_uint2(lo, hi);
    }
    // stage U -> LDS (same swizzle family)
    #pragma unroll
    for (int i = 0; i < 4; ++i){
        int g = tid + i*256;
        int urow = g >> 4, uc = g & 15;
        unsigned int b = ((unsigned int)(urow*256 + uc*16)) ^ ((unsigned int)(urow & 7) << 4);
        *(uint4*)(smem + 16384 + b) = uv[i];
    }
    __syncthreads();

    const int lane = tid & 63, wv = tid >> 6;
    const int lr = lane & 15, lg = lane >> 4;
    const int arow = wv*16 + lr;
    // A-frags from LDS
    bf16x8 af[4];
    #pragma unroll
    for (int kk = 0; kk < 4; ++kk){
        unsigned int ab = ((unsigned int)(arow*256 + kk*64 + lg*16)) ^ ((unsigned int)(arow & 7) << 4);
        af[kk] = *(const bf16x8*)(smem + ab);
    }
    // MFMA, B from global wT (L1-hot)
    f32x4 acc[8];
    #pragma unroll
    for (int n = 0; n < 8; ++n) acc[n] = (f32x4){0.f,0.f,0.f,0.f};
    #pragma unroll
    for (int kk = 0; kk < 4; ++kk){
        #pragma unroll
        for (int n = 0; n < 8; ++n){
            bf16x8 bw = *(const bf16x8*)(wT + (size_t)(n*16 + lr)*CH + kk*32 + lg*8);
            acc[n] = __builtin_amdgcn_mfma_f32_16x16x32_bf16(af[kk], bw, acc[n], 0, 0, 0);
        }
    }
    // epilogue (C/D: col=lane&15, row=(lane>>4)*4+reg)
    #pragma unroll
    for (int n = 0; n < 8; ++n){
        int cc = n*16 + lr;
        float s = 0.f, ss = 0.f;
        #pragma unroll
        for (int j = 0; j < 4; ++j){
            int ml = wv*16 + lg*4 + j;
            unsigned int b = ((unsigned int)(ml*256 + cc*2)) ^ ((unsigned int)(ml & 7) << 4);
            float r = bf2f(*(const unsigned short*)(smem + b));
            float u = bf2f(*(const unsigned short*)(smem + 16384 + b));
            float o0 = acc[n][j];
            float v = fmaf(o0, 0.5f*u, o0) + r;      // o0*(1+0.5(h+t)) + ea
            if (WRITE){
                out[(e0 + ml)*CH + cc] = fmaxf(fmaf(v, red[cc], red[CH + cc]), 0.f);
            } else {
                s += v; ss += v*v;
            }
        }
        if (!WRITE){
            s  += __shfl_xor(s, 16);  s  += __shfl_xor(s, 32);
            ss += __shfl_xor(ss, 16); ss += __shfl_xor(ss, 32);
            if (lane < 16){
                atomicAdd(&red[cc], s);
                atomicAdd(&red[CH + cc], ss);
            }
        }
    }
    if (!WRITE){
        __syncthreads();
        if (tid < 256) atomicAdd(&sums[(blockIdx.x & 255)*256 + tid], red[tid]);
    }
}

// ---------------------------------------------------------------------------
// k3: reduce 256 slots -> per-channel scale/shift (sb)
// ---------------------------------------------------------------------------
__global__ __launch_bounds__(128) void k3_stats(
        const float* __restrict__ sums, const float* __restrict__ gamma,
        const float* __restrict__ beta, float* __restrict__ sb, float invE){
    int c = threadIdx.x;
    float s = 0.f, ss = 0.f;
    for (int i = 0; i < 256; ++i){ s += sums[i*256 + c]; ss += sums[i*256 + CH + c]; }
    float mean = s * invE;
    float var = ss * invE - mean*mean;     // biased variance (matches reference)
    float inv = rsqrtf(var + 1e-5f);
    float sc = gamma[c] * inv;
    sb[c] = sc;
    sb[CH + c] = beta[c] - mean * sc;
}

// ---------------------------------------------------------------------------
// FALLBACK (small ws): R1's proven k2_main (287us) + k4_f32. f32 pre-BN path.
// ---------------------------------------------------------------------------
__global__ __launch_bounds__(512, 4) void k2_main(
        const float* __restrict__ ea, const int* __restrict__ eidx,
        const unsigned short* __restrict__ wT,
        const unsigned short* __restrict__ H, const unsigned short* __restrict__ T,
        float* __restrict__ out, float* __restrict__ sums, int E){
    __shared__ __align__(16) unsigned char smem[66560];
    float* red = (float*)(smem + 65536);
    const int tid = threadIdx.x;
    const int e0 = blockIdx.x * 128;
    if (tid < 256) red[tid] = 0.f;
    float4 eav[8];
    #pragma unroll
    for (int i = 0; i < 8; ++i){
        int g = tid + i*512;
        int row = g >> 5, col4 = (g & 31)*4;
        eav[i] = *(const float4*)(ea + (size_t)(e0+row)*CH + col4);
    }
    uint4 wv4[4];
    #pragma unroll
    for (int i = 0; i < 4; ++i){
        int g = tid + i*512;
        int n = g >> 4, k8 = (g & 15)*8;
        wv4[i] = *(const uint4*)(wT + n*CH + k8);
    }
    int ri4[4], ci4[4];
    #pragma unroll
    for (int i = 0; i < 4; ++i){
        int r = (tid + i*512) >> 4;
        ri4[i] = eidx[e0 + r];
        ci4[i] = eidx[E + e0 + r];
    }
    uint4 hv[4], tv[4];
    #pragma unroll
    for (int i = 0; i < 4; ++i){
        int c = (tid + i*512) & 15;
        hv[i] = *(const uint4*)(H + (size_t)ri4[i]*CH + c*8);
        tv[i] = *(const uint4*)(T + (size_t)ci4[i]*CH + c*8);
    }
    #pragma unroll
    for (int i = 0; i < 8; ++i){
        int g = tid + i*512;
        int row = g >> 5, col4 = (g & 31)*4;
        float4 v = eav[i];
        unsigned int lo = (unsigned int)f2bf(v.x) | ((unsigned int)f2bf(v.y) << 16);
        unsigned int hi = (unsigned int)f2bf(v.z) | ((unsigned int)f2bf(v.w) << 16);
        unsigned int b = ((unsigned int)(row*256 + col4*2)) ^ ((unsigned int)(row & 7) << 4);
        *(uint2*)(smem + b) = make_uint2(lo, hi);
    }
    #pragma unroll
    for (int i = 0; i < 4; ++i){
        int g = tid + i*512;
        int n = g >> 4, k8 = (g & 15)*8;
        unsigned int b = ((unsigned int)(n*256 + k8*2)) ^ ((unsigned int)(n & 7) << 4);
        *(uint4*)(smem + 32768 + b) = wv4[i];
    }
    __syncthreads();
    const int lane = tid & 63, wv = tid >> 6;
    const int lr = lane & 15, lg = lane >> 4;
    f32x4 acc[8];
    #pragma unroll
    for (int n = 0; n < 8; ++n) acc[n] = (f32x4){0.f,0.f,0.f,0.f};
    #pragma unroll
    for (int kk = 0; kk < 4; ++kk){
        int arow = wv*16 + lr;
        unsigned int ab = ((unsigned int)(arow*256 + kk*64 + lg*16)) ^ ((unsigned int)(arow & 7) << 4);
        bf16x8 a = *(const bf16x8*)(smem + ab);
        #pragma unroll
        for (int n = 0; n < 8; ++n){
            int cc = n*16 + lr;
            unsigned int bb = ((unsigned int)(cc*256 + kk*64 + lg*16)) ^ ((unsigned int)(cc & 7) << 4);
            bf16x8 bw = *(const bf16x8*)(smem + 32768 + bb);
            acc[n] = __builtin_amdgcn_mfma_f32_16x16x32_bf16(a, bw, acc[n], 0, 0, 0);
        }
    }
    float res[32];
    #pragma unroll
    for (int n = 0; n < 8; ++n){
        int cc = n*16 + lr;
        #pragma unroll
        for (int j = 0; j < 4; ++j){
            int ml = wv*16 + lg*4 + j;
            unsigned int b = ((unsigned int)(ml*256 + cc*2)) ^ ((unsigned int)(ml & 7) << 4);
            res[n*4 + j] = bf2f(*(const unsigned short*)(smem + b));
        }
    }
    __syncthreads();
    #pragma unroll
    for (int i = 0; i < 4; ++i){
        int g = tid + i*512;
        int r = g >> 4, c = g & 15;
        unsigned int b = ((unsigned int)(r*256 + c*16)) ^ ((unsigned int)((r >> 2) & 3) << 5);
        *(uint4*)(smem + b) = hv[i];
        *(uint4*)(smem + 32768 + b) = tv[i];
    }
    __syncthreads();
    #pragma unroll
    for (int n = 0; n < 8; ++n){
        int cc = n*16 + lr;
        float s = 0.f, ss = 0.f;
        #pragma unroll
        for (int j = 0; j < 4; ++j){
            int ml = wv*16 + lg*4 + j;
            unsigned int b = ((unsigned int)(ml*256 + cc*2)) ^ ((unsigned int)((ml >> 2) & 3) << 5);
            float h = bf2f(*(const unsigned short*)(smem + b));
            float t = bf2f(*(const unsigned short*)(smem + 32768 + b));
            float v = acc[n][j] * (1.f + 0.5f*(h + t)) + res[n*4 + j];
            out[(size_t)(e0 + ml)*CH + cc] = v;
            s += v; ss += v*v;
        }
        s  += __shfl_xor(s, 16);  s  += __shfl_xor(s, 32);
        ss += __shfl_xor(ss, 16); ss += __shfl_xor(ss, 32);
        if (lane < 16){
            atomicAdd(&red[cc], s);
            atomicAdd(&red[CH + cc], ss);
        }
    }
    __syncthreads();
    if (tid < 256) atomicAdd(&sums[(blockIdx.x & 255)*256 + tid], red[tid]);
}

__global__ __launch_bounds__(256) void k4_f32(
        float* __restrict__ out, const float* __restrict__ sb, int n4){
    int i = blockIdx.x * 256 + threadIdx.x;
    int stride = gridDim.x * 256;
    float4* o4 = (float4*)out;
    const float4* s4 = (const float4*)sb;
    for (; i < n4; i += stride){
        float4 v = o4[i];
        int c4 = i & 31;
        float4 sc = s4[c4], bi = s4[32 + c4];
        v.x = fmaxf(fmaf(v.x, sc.x, bi.x), 0.f);
        v.y = fmaxf(fmaf(v.y, sc.y, bi.y), 0.f);
        v.z = fmaxf(fmaf(v.z, sc.z, bi.z), 0.f);
        v.w = fmaxf(fmaf(v.w, sc.w, bi.w), 0.f);
        o4[i] = v;
    }
}

extern "C" void kernel_launch(void* const* d_in, const int* in_sizes, int n_in,
                              void* d_out, int out_size, void* d_ws, size_t ws_size,
                              hipStream_t stream) {
    const float* x      = (const float*)d_in[0];
    const int*   eidx   = (const int*)d_in[1];
    const float* ea     = (const float*)d_in[2];
    const float* w_self = (const float*)d_in[4];
    const float* w_h    = (const float*)d_in[5];
    const float* w_t    = (const float*)d_in[6];
    const float* gamma  = (const float*)d_in[7];
    const float* beta   = (const float*)d_in[8];
    float* out = (float*)d_out;

    const int N = in_sizes[0] / CH;     // 40000
    const int E = in_sizes[3];          // 640000

    // workspace carve-up:
    float* sums = (float*)d_ws;                          // 256*256 f32
    float* sb   = sums + 256*256;                        // 256 f32
    unsigned short* wT = (unsigned short*)(sb + 256);    // 3*128*128 bf16
    unsigned short* H  = wT + 3*CH*CH;                   // N*128 bf16
    unsigned short* T  = H + (size_t)N*CH;               // N*128 bf16
    unsigned short* U  = T + (size_t)N*CH;               // E*128 bf16 (if it fits)

    size_t base_ws = (size_t)(256*256 + 256)*4 + (size_t)3*CH*CH*2 + 2*(size_t)N*CH*2;
    size_t need_u  = base_ws + (size_t)E*CH*2;           // ~185 MB
    bool big_ws = (ws_size >= need_u);

    k0_prep<<<256, 256, 0, stream>>>(w_self, w_h, w_t, wT, sums);
    k1_ht  <<<(N + 127)/128, 512, 0, stream>>>(x, wT, H, T, N);
    if (big_ws){
        k2g    <<<2048, 256, 0, stream>>>(eidx, H, T, U, E);
        k2ab<0><<<E/64, 256, 0, stream>>>(ea, U, wT, nullptr, nullptr, sums, E);
        k3_stats<<<1, 128, 0, stream>>>(sums, gamma, beta, sb, 1.0f/(float)E);
        k2ab<1><<<E/64, 256, 0, stream>>>(ea, U, wT, out, sb, nullptr, E);
    } else {
        k2_main<<<E/128, 512, 0, stream>>>(ea, eidx, wT, H, T, out, sums, E);
        k3_stats<<<1, 128, 0, stream>>>(sums, gamma, beta, sb, 1.0f/(float)E);
        k4_f32<<<2048, 256, 0, stream>>>(out, sb, E*CH/4);
    }
}